// Round 1
// baseline (152.469 us; speedup 1.0000x reference)
//
#include <hip/hip_runtime.h>

#define NB 4
#define SEQ 16384
#define D 64
#define NH 8
#define INNER 512

// ---------------------------------------------------------------------------
// Kernel 1: S[b] = keys[b]^T @ values[b]   (64x64 f32 per batch)
// grid (SEQ/S_RPB, NB), block 256. Partial sums in regs, atomicAdd at end.
// ---------------------------------------------------------------------------
constexpr int S_RPB  = 256;   // rows per block
constexpr int S_TILE = 32;    // rows staged in LDS per iteration

__global__ __launch_bounds__(256) void k_S(const float* __restrict__ keys,
                                           const float* __restrict__ values,
                                           float* __restrict__ S) {
    __shared__ float ks[S_TILE][D];
    __shared__ float vs[S_TILE][D];
    const int b = blockIdx.y;
    const int t = threadIdx.x;
    const size_t base = ((size_t)b * SEQ + (size_t)blockIdx.x * S_RPB) * D;
    const float4* ksrc = (const float4*)(keys + base);
    const float4* vsrc = (const float4*)(values + base);
    const int di = t >> 4;    // 0..15 : keys-channel group
    const int ej = t & 15;    // 0..15 : values-channel group
    float acc[4][4] = {{0.f}};
    for (int tile = 0; tile < S_RPB / S_TILE; ++tile) {
        float4* kd = (float4*)&ks[0][0];
        float4* vd = (float4*)&vs[0][0];
        const int off = tile * (S_TILE * D / 4);
        kd[t]       = ksrc[off + t];
        kd[t + 256] = ksrc[off + t + 256];
        vd[t]       = vsrc[off + t];
        vd[t + 256] = vsrc[off + t + 256];
        __syncthreads();
        #pragma unroll 8
        for (int n = 0; n < S_TILE; ++n) {
            float kv[4], vv[4];
            #pragma unroll
            for (int a = 0; a < 4; ++a) kv[a] = ks[n][di + 16 * a];
            #pragma unroll
            for (int c = 0; c < 4; ++c) vv[c] = vs[n][ej + 16 * c];
            #pragma unroll
            for (int a = 0; a < 4; ++a)
                #pragma unroll
                for (int c = 0; c < 4; ++c)
                    acc[a][c] = fmaf(kv[a], vv[c], acc[a][c]);
        }
        __syncthreads();
    }
    float* Sb = S + b * D * D;
    #pragma unroll
    for (int a = 0; a < 4; ++a)
        #pragma unroll
        for (int c = 0; c < 4; ++c)
            atomicAdd(&Sb[(di + 16 * a) * D + (ej + 16 * c)], acc[a][c]);
}

// ---------------------------------------------------------------------------
// Kernel 2: G[b] = (1/SEQ) * sum_h Wq_h^T @ (Wk_h @ S[b] @ Wk_h^T) @ Wout_h^T
// grid NB*NH (one block per (b,h)), block 256. atomicAdd over h into G[b].
// ---------------------------------------------------------------------------
__global__ __launch_bounds__(256) void k_G(const float* __restrict__ S,
                                           const float* __restrict__ Wq,
                                           const float* __restrict__ Wk,
                                           const float* __restrict__ Wout,
                                           float* __restrict__ G) {
    __shared__ float Ss[D][D];
    __shared__ float W1[D][D];
    __shared__ float T1[D][D];
    __shared__ float T2[D][D];
    const int b = blockIdx.x >> 3;
    const int h = blockIdx.x & 7;
    const int t = threadIdx.x;
    const int di = t >> 4, ej = t & 15;

    const float* Sb  = S + b * D * D;
    const float* Wkh = Wk + h * D * D;   // Wk row-major [512][64]; head = 64 contiguous rows
    for (int i = t; i < D * D; i += 256) {
        (&Ss[0][0])[i] = Sb[i];
        (&W1[0][0])[i] = Wkh[i];
    }
    __syncthreads();

    float acc[4][4];

    // T1 = Wk_h @ S : T1[d][e] = sum_i W1[d][i] * Ss[i][e]
    #pragma unroll
    for (int a = 0; a < 4; ++a)
        #pragma unroll
        for (int c = 0; c < 4; ++c) acc[a][c] = 0.f;
    for (int i = 0; i < D; ++i) {
        float wa[4], sv[4];
        #pragma unroll
        for (int a = 0; a < 4; ++a) wa[a] = W1[di + 16 * a][i];
        #pragma unroll
        for (int c = 0; c < 4; ++c) sv[c] = Ss[i][ej + 16 * c];
        #pragma unroll
        for (int a = 0; a < 4; ++a)
            #pragma unroll
            for (int c = 0; c < 4; ++c) acc[a][c] = fmaf(wa[a], sv[c], acc[a][c]);
    }
    #pragma unroll
    for (int a = 0; a < 4; ++a)
        #pragma unroll
        for (int c = 0; c < 4; ++c) T1[di + 16 * a][ej + 16 * c] = acc[a][c];
    __syncthreads();

    // T2 = T1 @ Wk_h^T : T2[d][e] = sum_i T1[d][i] * W1[e][i]
    #pragma unroll
    for (int a = 0; a < 4; ++a)
        #pragma unroll
        for (int c = 0; c < 4; ++c) acc[a][c] = 0.f;
    for (int i = 0; i < D; ++i) {
        float ta[4], wb[4];
        #pragma unroll
        for (int a = 0; a < 4; ++a) ta[a] = T1[di + 16 * a][i];
        #pragma unroll
        for (int c = 0; c < 4; ++c) wb[c] = W1[ej + 16 * c][i];
        #pragma unroll
        for (int a = 0; a < 4; ++a)
            #pragma unroll
            for (int c = 0; c < 4; ++c) acc[a][c] = fmaf(ta[a], wb[c], acc[a][c]);
    }
    #pragma unroll
    for (int a = 0; a < 4; ++a)
        #pragma unroll
        for (int c = 0; c < 4; ++c) T2[di + 16 * a][ej + 16 * c] = acc[a][c];
    __syncthreads();

    // W1 <- Wq_h
    const float* Wqh = Wq + h * D * D;
    for (int i = t; i < D * D; i += 256) (&W1[0][0])[i] = Wqh[i];
    __syncthreads();

    // T3 = Wq_h^T @ T2 : T3[d][e] = sum_i W1[i][d] * T2[i][e]  -> store into T1
    #pragma unroll
    for (int a = 0; a < 4; ++a)
        #pragma unroll
        for (int c = 0; c < 4; ++c) acc[a][c] = 0.f;
    for (int i = 0; i < D; ++i) {
        float wa[4], tb[4];
        #pragma unroll
        for (int a = 0; a < 4; ++a) wa[a] = W1[i][di + 16 * a];
        #pragma unroll
        for (int c = 0; c < 4; ++c) tb[c] = T2[i][ej + 16 * c];
        #pragma unroll
        for (int a = 0; a < 4; ++a)
            #pragma unroll
            for (int c = 0; c < 4; ++c) acc[a][c] = fmaf(wa[a], tb[c], acc[a][c]);
    }
    #pragma unroll
    for (int a = 0; a < 4; ++a)
        #pragma unroll
        for (int c = 0; c < 4; ++c) T1[di + 16 * a][ej + 16 * c] = acc[a][c];
    __syncthreads();

    // W1 <- Wout_h^T rows: W1[e][i] = Wout[e][h*64 + i]  (Wout row-major [64][512])
    for (int i = t; i < D * D; i += 256) {
        int r = i >> 6, c2 = i & 63;
        (&W1[0][0])[i] = Wout[r * INNER + h * D + c2];
    }
    __syncthreads();

    // T4 = T3 @ Wout_h^T, accumulate into G[b] with 1/SEQ
    #pragma unroll
    for (int a = 0; a < 4; ++a)
        #pragma unroll
        for (int c = 0; c < 4; ++c) acc[a][c] = 0.f;
    for (int i = 0; i < D; ++i) {
        float ta[4], wb[4];
        #pragma unroll
        for (int a = 0; a < 4; ++a) ta[a] = T1[di + 16 * a][i];
        #pragma unroll
        for (int c = 0; c < 4; ++c) wb[c] = W1[ej + 16 * c][i];
        #pragma unroll
        for (int a = 0; a < 4; ++a)
            #pragma unroll
            for (int c = 0; c < 4; ++c) acc[a][c] = fmaf(ta[a], wb[c], acc[a][c]);
    }
    const float invn = 1.0f / (float)SEQ;
    float* Gb = G + b * D * D;
    #pragma unroll
    for (int a = 0; a < 4; ++a)
        #pragma unroll
        for (int c = 0; c < 4; ++c)
            atomicAdd(&Gb[(di + 16 * a) * D + (ej + 16 * c)], acc[a][c] * invn);
}

// ---------------------------------------------------------------------------
// Kernel 3: out[b,n,:] = queries[b,n,:] @ G[b] + bout
// grid (SEQ/A_ROWS, NB), block 256.
// ---------------------------------------------------------------------------
constexpr int A_ROWS = 64;

__global__ __launch_bounds__(256) void k_apply(const float* __restrict__ queries,
                                               const float* __restrict__ G,
                                               const float* __restrict__ bout,
                                               float* __restrict__ out) {
    __shared__ float Gs[D][D];          // [c][f]
    __shared__ float qs[A_ROWS][D + 4]; // +4 pad: keeps float4 alignment, breaks bank stride
    const int b = blockIdx.y;
    const int t = threadIdx.x;
    const size_t base = ((size_t)b * SEQ + (size_t)blockIdx.x * A_ROWS) * D;
    const float4* qsrc = (const float4*)(queries + base);
    const float4* Gsrc = (const float4*)(G + b * D * D);
    float4* Gd = (float4*)&Gs[0][0];
    #pragma unroll
    for (int i = 0; i < 4; ++i) {
        const int idx = t + 256 * i;
        Gd[idx] = Gsrc[idx];
        float4 qv = qsrc[idx];
        const int r = idx >> 4;          // 16 float4 per 64-float row
        const int c = (idx & 15) * 4;
        *(float4*)&qs[r][c] = qv;
    }
    __syncthreads();

    const int d4 = (t & 15) * 4;  // output-feature group (4 consecutive)
    const int rg = t >> 4;        // row group: rows rg, rg+16, rg+32, rg+48
    const float4 bo = *(const float4*)&bout[d4];
    float acc[4][4] = {{0.f}};    // [row][feature]
    #pragma unroll 8
    for (int i = 0; i < D; ++i) {
        const float4 g = *(const float4*)&Gs[i][d4];
        #pragma unroll
        for (int r = 0; r < 4; ++r) {
            const float qv = qs[rg + 16 * r][i];
            acc[r][0] = fmaf(qv, g.x, acc[r][0]);
            acc[r][1] = fmaf(qv, g.y, acc[r][1]);
            acc[r][2] = fmaf(qv, g.z, acc[r][2]);
            acc[r][3] = fmaf(qv, g.w, acc[r][3]);
        }
    }
    float* ob = out + base;
    #pragma unroll
    for (int r = 0; r < 4; ++r) {
        float4 o = make_float4(acc[r][0] + bo.x, acc[r][1] + bo.y,
                               acc[r][2] + bo.z, acc[r][3] + bo.w);
        *(float4*)&ob[(rg + 16 * r) * D + d4] = o;
    }
}

extern "C" void kernel_launch(void* const* d_in, const int* in_sizes, int n_in,
                              void* d_out, int out_size, void* d_ws, size_t ws_size,
                              hipStream_t stream) {
    const float* queries = (const float*)d_in[0];
    const float* keys    = (const float*)d_in[1];
    const float* values  = (const float*)d_in[2];
    const float* Wq      = (const float*)d_in[3];
    const float* Wk      = (const float*)d_in[4];
    const float* Wout    = (const float*)d_in[5];
    const float* bout    = (const float*)d_in[6];
    float* out = (float*)d_out;

    float* S = (float*)d_ws;               // NB * 64*64
    float* G = S + NB * D * D;             // NB * 64*64
    hipMemsetAsync(d_ws, 0, (size_t)2 * NB * D * D * sizeof(float), stream);

    k_S<<<dim3(SEQ / S_RPB, NB), 256, 0, stream>>>(keys, values, S);
    k_G<<<NB * NH, 256, 0, stream>>>(S, Wq, Wk, Wout, G);
    k_apply<<<dim3(SEQ / A_ROWS, NB), 256, 0, stream>>>(queries, G, bout, out);
}